// Round 9
// baseline (418.234 us; speedup 1.0000x reference)
//
#include <hip/hip_runtime.h>
#include <hip/hip_bf16.h>
#include <stdint.h>

// CapsuleLayer dynamic routing via bf16 MFMA (16x16x32), unified 3-pass design.
// B=512, R=1152, C=10, O=16, I=8.
// R8 lesson: latency-bound at 16.5% occupancy (43.5KB LDS -> 3 blocks/CU,
// grid 768 = 3/CU exactly). This round: NSPLIT 48 (grid 1536), LDS partial
// combine via atomic spart[2720] (10.9 KB, x17 bank padding, R7-proven),
// global atomicAdd into s (no P array, no squash_merge gather).
// A-frag = W's natural order in bf16 (Wf); D-layout HW-verified:
// lane l: b=l&15, co=(l>>4)*4+reg; agreement = 4 FMA + xor16 + xor32.
// ws: v f32[81920] | s f32[81920] | bij bf16[1152*10*512] | Wf bf16[1474560]
//   = 15.4 MB (< 24.25 MB proven).

#define BB 512
#define RR 1152
#define CCAP 10
#define II 8
#define CO 160
#define NBT 32       // b-tiles of 16
#define NSPLIT 48    // r-chunks
#define RCHUNK 24    // r per block
#define RWAVE 6      // r per wave

typedef __attribute__((ext_vector_type(8))) short bf16x8;
typedef __attribute__((ext_vector_type(4))) float f32x4;

__device__ inline short f2bf(float f) {
    uint32_t b = __float_as_uint(f);
    uint32_t r = (b + 0x7FFFu + ((b >> 16) & 1u)) >> 16;
    return (short)r;
}
__device__ inline float bf2f(unsigned short u) {
    return __uint_as_float(((uint32_t)u) << 16);
}

// ---- one-time W -> bf16 (natural order == fragment order) ----
__global__ __launch_bounds__(256) void wconv(
    const float* __restrict__ W, unsigned short* __restrict__ Wf)
{
    const int i = (blockIdx.x * 256 + threadIdx.x) * 4;  // 1,474,560 total
    f32x4 w = *reinterpret_cast<const f32x4*>(W + i);
    ushort4 o;
    o.x = (unsigned short)f2bf(w[0]); o.y = (unsigned short)f2bf(w[1]);
    o.z = (unsigned short)f2bf(w[2]); o.w = (unsigned short)f2bf(w[3]);
    *reinterpret_cast<ushort4*>(Wf + i) = o;
}

// ---- unified routing pass (K=0: c=0.1; K=1: store bij; K=2: load bij) ----
template <int K>
__global__ __launch_bounds__(256) void route3(
    const float* __restrict__ x, const unsigned short* __restrict__ Wf,
    const float* __restrict__ v_in, unsigned short* __restrict__ bij,
    float* __restrict__ s_out)
{
    __shared__ float spart[CO * 17];   // 10.9 KB, x17 padding
    const int t  = threadIdx.x;
    const int bt = blockIdx.x & 31;
    const int sp = blockIdx.x >> 5;    // 0..47
    const int b0 = bt * 16;
    const int w  = t >> 6;
    const int l  = t & 63;
    const int lg = l >> 4;
    const int ln = l & 15;

    for (int i = t; i < CO * 17; i += 256) spart[i] = 0.0f;

    // v fragment (persistent): vf[tt][reg] = v[b0+ln][tt*16 + lg*4 + reg]
    f32x4 vf[CCAP];
    if (K > 0) {
        #pragma unroll
        for (int tt = 0; tt < CCAP; ++tt)
            vf[tt] = *reinterpret_cast<const f32x4*>(
                v_in + (size_t)(b0 + ln) * CO + tt * 16 + lg * 4);
    }

    f32x4 sacc[CCAP];
    #pragma unroll
    for (int tt = 0; tt < CCAP; ++tt) {
        sacc[tt][0]=0.f; sacc[tt][1]=0.f; sacc[tt][2]=0.f; sacc[tt][3]=0.f;
    }

    const int rb = sp * RCHUNK + w * RWAVE;
    for (int rr = 0; rr < RWAVE; ++rr) {
        const int r = rb + rr;
        // x fragment (B operand): lanes 0..15 hold k=0..7 = i; rest MUST be zero
        bf16x8 bfr;
        #pragma unroll
        for (int j = 0; j < 8; ++j) bfr[j] = 0;
        if (l < 16) {
            const float* xp = x + ((size_t)(b0 + l) * RR + r) * II;
            f32x4 lo = *reinterpret_cast<const f32x4*>(xp);
            f32x4 hi = *reinterpret_cast<const f32x4*>(xp + 4);
            #pragma unroll
            for (int j = 0; j < 4; ++j) { bfr[j] = f2bf(lo[j]); bfr[4+j] = f2bf(hi[j]); }
        }
        // u tiles: one MFMA per capsule. A-frag loaded unconditionally
        // (broadcast across lg); k>=8 slots see zero B so A garbage is harmless.
        f32x4 u[CCAP];
        #pragma unroll
        for (int tt = 0; tt < CCAP; ++tt) {
            bf16x8 afr = *reinterpret_cast<const bf16x8*>(
                Wf + ((size_t)r * CCAP + tt) * 128 + ln * 8);
            f32x4 z; z[0]=0.f; z[1]=0.f; z[2]=0.f; z[3]=0.f;
            u[tt] = __builtin_amdgcn_mfma_f32_16x16x32_bf16(afr, bfr, z, 0, 0, 0);
        }
        if (K > 0) {
            // agreement a[b,c] = sum_o u*v  (o = lg*4+reg; xor16/32 completes)
            float a[CCAP];
            #pragma unroll
            for (int tt = 0; tt < CCAP; ++tt) {
                float p = u[tt][0]*vf[tt][0] + u[tt][1]*vf[tt][1]
                        + u[tt][2]*vf[tt][2] + u[tt][3]*vf[tt][3];
                p += __shfl_xor(p, 16);
                p += __shfl_xor(p, 32);
                a[tt] = p;
            }
            if (K == 2) {
                #pragma unroll
                for (int tt = 0; tt < CCAP; ++tt)
                    a[tt] += bf2f(bij[((size_t)r * CCAP + tt) * BB + b0 + ln]);
            } else {
                if (l < 16) {
                    #pragma unroll
                    for (int tt = 0; tt < CCAP; ++tt)
                        bij[((size_t)r * CCAP + tt) * BB + b0 + l] =
                            (unsigned short)f2bf(a[tt]);
                }
            }
            // softmax over capsules (in-register)
            float m = a[0];
            #pragma unroll
            for (int tt = 1; tt < CCAP; ++tt) m = fmaxf(m, a[tt]);
            float ssum = 0.f;
            #pragma unroll
            for (int tt = 0; tt < CCAP; ++tt) { a[tt] = __expf(a[tt] - m); ssum += a[tt]; }
            float inv = 1.0f / ssum;
            #pragma unroll
            for (int tt = 0; tt < CCAP; ++tt) {
                float c = a[tt] * inv;
                sacc[tt][0] += c * u[tt][0];
                sacc[tt][1] += c * u[tt][1];
                sacc[tt][2] += c * u[tt][2];
                sacc[tt][3] += c * u[tt][3];
            }
        } else {
            #pragma unroll
            for (int tt = 0; tt < CCAP; ++tt) {
                sacc[tt][0] += u[tt][0];
                sacc[tt][1] += u[tt][1];
                sacc[tt][2] += u[tt][2];
                sacc[tt][3] += u[tt][3];
            }
        }
    }
    if (K == 0) {
        #pragma unroll
        for (int tt = 0; tt < CCAP; ++tt) {
            sacc[tt][0] *= 0.1f; sacc[tt][1] *= 0.1f;
            sacc[tt][2] *= 0.1f; sacc[tt][3] *= 0.1f;
        }
    }
    __syncthreads();   // spart zero-init visible
    // combine 4 waves: lane's (b,co) is unique within its wave; 4-way LDS atomics
    #pragma unroll
    for (int tt = 0; tt < CCAP; ++tt) {
        #pragma unroll
        for (int reg = 0; reg < 4; ++reg)
            atomicAdd(&spart[(tt * 16 + lg * 4 + reg) * 17 + ln], sacc[tt][reg]);
    }
    __syncthreads();
    // one global atomic per (b,co) per block, coalesced over co
    for (int q = 0; q < 10; ++q) {
        const int idx = q * 256 + t;          // < 2560
        const int co = idx % CO, b16 = idx / CO;
        atomicAdd(&s_out[(size_t)(b0 + b16) * CO + co], spart[co * 17 + b16]);
    }
}

// ---- bias + squash ----
__global__ __launch_bounds__(256) void squash_plain(
    const float* __restrict__ s, const float* __restrict__ bias,
    float* __restrict__ v_out)
{
    const int idx = blockIdx.x * 256 + threadIdx.x;   // < 81920
    const int co = idx % CO;
    float sv = s[idx] + bias[co];
    float n2 = sv * sv;
    n2 += __shfl_xor(n2, 1);
    n2 += __shfl_xor(n2, 2);
    n2 += __shfl_xor(n2, 4);
    n2 += __shfl_xor(n2, 8);
    float norm = sqrtf(n2);
    float scale = norm / (1.0f + n2 + 1e-8f);
    v_out[idx] = scale * sv;
}

extern "C" void kernel_launch(void* const* d_in, const int* in_sizes, int n_in,
                              void* d_out, int out_size, void* d_ws, size_t ws_size,
                              hipStream_t stream) {
    const float* x    = (const float*)d_in[0];
    const float* W    = (const float*)d_in[1];
    const float* bias = (const float*)d_in[2];
    float* out = (float*)d_out;

    float* v = (float*)d_ws;                               // 81,920 f32
    float* s = v + 81920;                                  // 81,920 f32
    unsigned short* bij = (unsigned short*)(s + 81920);    // 5,898,240 bf16
    unsigned short* Wf  = bij + (size_t)RR * CCAP * BB;    // 1,474,560 bf16

    const dim3 blk(256);
    const dim3 rgrid(NBT * NSPLIT);   // 1536

    wconv<<<1440, blk, 0, stream>>>(W, Wf);

    hipMemsetAsync(s, 0, 81920 * sizeof(float), stream);
    route3<0><<<rgrid, blk, 0, stream>>>(x, Wf, v, bij, s);
    squash_plain<<<320, blk, 0, stream>>>(s, bias, v);

    hipMemsetAsync(s, 0, 81920 * sizeof(float), stream);
    route3<1><<<rgrid, blk, 0, stream>>>(x, Wf, v, bij, s);
    squash_plain<<<320, blk, 0, stream>>>(s, bias, v);

    hipMemsetAsync(s, 0, 81920 * sizeof(float), stream);
    route3<2><<<rgrid, blk, 0, stream>>>(x, Wf, v, bij, s);
    squash_plain<<<320, blk, 0, stream>>>(s, bias, out);
}

// Round 10
// 326.098 us; speedup vs baseline: 1.2825x; 1.2825x over previous
//
#include <hip/hip_runtime.h>
#include <hip/hip_bf16.h>
#include <stdint.h>

// CapsuleLayer dynamic routing — fp16 u_hat materialization (streaming design).
// B=512, R=1152, C=10, O=16, I=8, 3 iters.
// R9 lesson: recompute-u passes are latency-bound (K=0 == K=2 duration) because
// 10 u-tiles + sacc + vf stay live across softmax -> register/AGPR bloat + exposed
// L2 fragment-load latency. New design:
//   producer: MFMA per (r,c) tile, consume u IMMEDIATELY (store fp16 + sacc).
//             Fragment-major U layout -> 8B/lane fully coalesced stores.
//   consumers (pass 1,2): NO MFMA; stream U back (8B/lane coalesced), u held
//             packed fp16 (20 VGPR), cvt on the fly. Memory-roofline bound.
// Falls back to the proven R8 kernels if ws_size < 213.6 MB.
// big ws: v f32 | s f32 | Wf bf16 | xT bf16[r][b][i] | bij f16[r][c][b] | U f16

#define BB 512
#define RR 1152
#define CCAP 10
#define II 8
#define CO 160
#define NBT 32
#define NSPLIT 24
#define RCHUNK 48
#define RWAVE 12

typedef __attribute__((ext_vector_type(8))) short bf16x8;
typedef __attribute__((ext_vector_type(4))) float f32x4;
typedef __attribute__((ext_vector_type(4))) _Float16 f16x4;

__device__ inline short f2bf(float f) {
    uint32_t b = __float_as_uint(f);
    uint32_t r = (b + 0x7FFFu + ((b >> 16) & 1u)) >> 16;
    return (short)r;
}
__device__ inline float bf2f(unsigned short u) {
    return __uint_as_float(((uint32_t)u) << 16);
}

// ---- prep: W -> bf16 (natural order == A-fragment order) ----
__global__ __launch_bounds__(256) void wconv(
    const float* __restrict__ W, unsigned short* __restrict__ Wf)
{
    const int i = (blockIdx.x * 256 + threadIdx.x) * 4;  // 1,474,560 total
    f32x4 w = *reinterpret_cast<const f32x4*>(W + i);
    ushort4 o;
    o.x = (unsigned short)f2bf(w[0]); o.y = (unsigned short)f2bf(w[1]);
    o.z = (unsigned short)f2bf(w[2]); o.w = (unsigned short)f2bf(w[3]);
    *reinterpret_cast<ushort4*>(Wf + i) = o;
}

// ---- prep: x[b][r][i] f32 -> xT[r][b][i] bf16 (coalesced B-fragments) ----
__global__ __launch_bounds__(256) void xconv(
    const float* __restrict__ x, unsigned short* __restrict__ xT)
{
    const int tid = blockIdx.x * 256 + threadIdx.x;   // < 589,824
    const int r = tid >> 9, b = tid & 511;
    const float* xp = x + ((size_t)b * RR + r) * II;
    f32x4 lo = *reinterpret_cast<const f32x4*>(xp);
    f32x4 hi = *reinterpret_cast<const f32x4*>(xp + 4);
    ushort4 o0, o1;
    o0.x=(unsigned short)f2bf(lo[0]); o0.y=(unsigned short)f2bf(lo[1]);
    o0.z=(unsigned short)f2bf(lo[2]); o0.w=(unsigned short)f2bf(lo[3]);
    o1.x=(unsigned short)f2bf(hi[0]); o1.y=(unsigned short)f2bf(hi[1]);
    o1.z=(unsigned short)f2bf(hi[2]); o1.w=(unsigned short)f2bf(hi[3]);
    unsigned short* op = xT + ((size_t)r * BB + b) * II;
    *reinterpret_cast<ushort4*>(op)     = o0;
    *reinterpret_cast<ushort4*>(op + 4) = o1;
}

// ---- producer: U tiles (fp16, fragment-major) + s0 = 0.1*sum_r u ----
__global__ __launch_bounds__(256) void produce_u(
    const unsigned short* __restrict__ xT, const unsigned short* __restrict__ Wf,
    _Float16* __restrict__ U, float* __restrict__ s_out)
{
    __shared__ float spart[CO * 17];
    const int t  = threadIdx.x;
    const int bt = blockIdx.x & 31;
    const int sp = blockIdx.x >> 5;
    const int b0 = bt * 16;
    const int w  = t >> 6;
    const int l  = t & 63;
    const int lg = l >> 4;
    const int ln = l & 15;

    for (int i = t; i < CO * 17; i += 256) spart[i] = 0.0f;

    f32x4 sacc[CCAP];
    #pragma unroll
    for (int tt = 0; tt < CCAP; ++tt) {
        sacc[tt][0]=0.f; sacc[tt][1]=0.f; sacc[tt][2]=0.f; sacc[tt][3]=0.f;
    }

    const int rb = sp * RCHUNK + w * RWAVE;
    for (int rr = 0; rr < RWAVE; ++rr) {
        const int r = rb + rr;
        bf16x8 bfr;
        #pragma unroll
        for (int j = 0; j < 8; ++j) bfr[j] = 0;
        if (l < 16)
            bfr = *reinterpret_cast<const bf16x8*>(xT + ((size_t)r * BB + b0 + l) * II);
        _Float16* Ub = U + ((size_t)bt * RR + r) * (CCAP * 256) + l * 4;
        #pragma unroll
        for (int tt = 0; tt < CCAP; ++tt) {
            bf16x8 afr = *reinterpret_cast<const bf16x8*>(
                Wf + ((size_t)r * CCAP + tt) * 128 + ln * 8);
            f32x4 z; z[0]=0.f; z[1]=0.f; z[2]=0.f; z[3]=0.f;
            f32x4 u = __builtin_amdgcn_mfma_f32_16x16x32_bf16(afr, bfr, z, 0, 0, 0);
            f16x4 h;
            h[0]=(_Float16)u[0]; h[1]=(_Float16)u[1];
            h[2]=(_Float16)u[2]; h[3]=(_Float16)u[3];
            *reinterpret_cast<f16x4*>(Ub + tt * 256) = h;
            sacc[tt][0] += u[0]; sacc[tt][1] += u[1];
            sacc[tt][2] += u[2]; sacc[tt][3] += u[3];
        }
    }
    __syncthreads();
    #pragma unroll
    for (int tt = 0; tt < CCAP; ++tt) {
        #pragma unroll
        for (int reg = 0; reg < 4; ++reg)
            atomicAdd(&spart[(tt * 16 + lg * 4 + reg) * 17 + ln], 0.1f * sacc[tt][reg]);
    }
    __syncthreads();
    for (int q = 0; q < 10; ++q) {
        const int idx = q * 256 + t;
        const int co = idx % CO, b16 = idx / CO;
        atomicAdd(&s_out[(size_t)(b0 + b16) * CO + co], spart[co * 17 + b16]);
    }
}

// ---- consumer passes 1,2: stream U, routing math, no MFMA ----
template <int K>
__global__ __launch_bounds__(256) void consume_u(
    const _Float16* __restrict__ U, const float* __restrict__ v_in,
    _Float16* __restrict__ bij, float* __restrict__ s_out)
{
    __shared__ float spart[CO * 17];
    const int t  = threadIdx.x;
    const int bt = blockIdx.x & 31;
    const int sp = blockIdx.x >> 5;
    const int b0 = bt * 16;
    const int w  = t >> 6;
    const int l  = t & 63;
    const int lg = l >> 4;
    const int ln = l & 15;

    for (int i = t; i < CO * 17; i += 256) spart[i] = 0.0f;

    f32x4 vf[CCAP];
    #pragma unroll
    for (int tt = 0; tt < CCAP; ++tt)
        vf[tt] = *reinterpret_cast<const f32x4*>(
            v_in + (size_t)(b0 + ln) * CO + tt * 16 + lg * 4);

    f32x4 sacc[CCAP];
    #pragma unroll
    for (int tt = 0; tt < CCAP; ++tt) {
        sacc[tt][0]=0.f; sacc[tt][1]=0.f; sacc[tt][2]=0.f; sacc[tt][3]=0.f;
    }

    const int rb = sp * RCHUNK + w * RWAVE;
    for (int rr = 0; rr < RWAVE; ++rr) {
        const int r = rb + rr;
        const _Float16* Ub = U + ((size_t)bt * RR + r) * (CCAP * 256) + l * 4;
        f16x4 uh[CCAP];                      // packed: 20 VGPRs total
        #pragma unroll
        for (int tt = 0; tt < CCAP; ++tt)
            uh[tt] = *reinterpret_cast<const f16x4*>(Ub + tt * 256);
        float a[CCAP];
        #pragma unroll
        for (int tt = 0; tt < CCAP; ++tt) {
            float p = (float)uh[tt][0]*vf[tt][0] + (float)uh[tt][1]*vf[tt][1]
                    + (float)uh[tt][2]*vf[tt][2] + (float)uh[tt][3]*vf[tt][3];
            p += __shfl_xor(p, 16);
            p += __shfl_xor(p, 32);
            a[tt] = p;
        }
        if (K == 2) {
            #pragma unroll
            for (int tt = 0; tt < CCAP; ++tt)
                a[tt] += (float)bij[((size_t)r * CCAP + tt) * BB + b0 + ln];
        } else {
            if (l < 16) {
                #pragma unroll
                for (int tt = 0; tt < CCAP; ++tt)
                    bij[((size_t)r * CCAP + tt) * BB + b0 + l] = (_Float16)a[tt];
            }
        }
        float m = a[0];
        #pragma unroll
        for (int tt = 1; tt < CCAP; ++tt) m = fmaxf(m, a[tt]);
        float ssum = 0.f;
        #pragma unroll
        for (int tt = 0; tt < CCAP; ++tt) { a[tt] = __expf(a[tt] - m); ssum += a[tt]; }
        float inv = 1.0f / ssum;
        #pragma unroll
        for (int tt = 0; tt < CCAP; ++tt) {
            float c = a[tt] * inv;
            sacc[tt][0] += c * (float)uh[tt][0];
            sacc[tt][1] += c * (float)uh[tt][1];
            sacc[tt][2] += c * (float)uh[tt][2];
            sacc[tt][3] += c * (float)uh[tt][3];
        }
    }
    __syncthreads();
    #pragma unroll
    for (int tt = 0; tt < CCAP; ++tt) {
        #pragma unroll
        for (int reg = 0; reg < 4; ++reg)
            atomicAdd(&spart[(tt * 16 + lg * 4 + reg) * 17 + ln], sacc[tt][reg]);
    }
    __syncthreads();
    for (int q = 0; q < 10; ++q) {
        const int idx = q * 256 + t;
        const int co = idx % CO, b16 = idx / CO;
        atomicAdd(&s_out[(size_t)(b0 + b16) * CO + co], spart[co * 17 + b16]);
    }
}

// ---- bias + squash ----
__global__ __launch_bounds__(256) void squash_plain(
    const float* __restrict__ s, const float* __restrict__ bias,
    float* __restrict__ v_out)
{
    const int idx = blockIdx.x * 256 + threadIdx.x;   // < 81920
    const int co = idx % CO;
    float sv = s[idx] + bias[co];
    float n2 = sv * sv;
    n2 += __shfl_xor(n2, 1);
    n2 += __shfl_xor(n2, 2);
    n2 += __shfl_xor(n2, 4);
    n2 += __shfl_xor(n2, 8);
    float norm = sqrtf(n2);
    float scale = norm / (1.0f + n2 + 1e-8f);
    v_out[idx] = scale * sv;
}

// ================= fallback (proven R8 path, ws < 213.6 MB) =================
template <int K>
__global__ __launch_bounds__(256) void route2(
    const float* __restrict__ x, const unsigned short* __restrict__ Wf,
    const float* __restrict__ v_in, unsigned short* __restrict__ bij,
    float* __restrict__ P)
{
    __shared__ float part[4 * 2720];
    const int t  = threadIdx.x;
    const int bt = blockIdx.x & 31;
    const int sp = blockIdx.x >> 5;
    const int b0 = bt * 16;
    const int w  = t >> 6;
    const int l  = t & 63;
    const int lg = l >> 4;
    const int ln = l & 15;

    f32x4 vf[CCAP];
    if (K > 0) {
        #pragma unroll
        for (int tt = 0; tt < CCAP; ++tt)
            vf[tt] = *reinterpret_cast<const f32x4*>(
                v_in + (size_t)(b0 + ln) * CO + tt * 16 + lg * 4);
    }
    f32x4 sacc[CCAP];
    #pragma unroll
    for (int tt = 0; tt < CCAP; ++tt) {
        sacc[tt][0]=0.f; sacc[tt][1]=0.f; sacc[tt][2]=0.f; sacc[tt][3]=0.f;
    }
    const int rb = sp * RCHUNK + w * RWAVE;
    for (int rr = 0; rr < RWAVE; ++rr) {
        const int r = rb + rr;
        bf16x8 bfr;
        #pragma unroll
        for (int j = 0; j < 8; ++j) bfr[j] = 0;
        if (l < 16) {
            const float* xp = x + ((size_t)(b0 + l) * RR + r) * II;
            f32x4 lo = *reinterpret_cast<const f32x4*>(xp);
            f32x4 hi = *reinterpret_cast<const f32x4*>(xp + 4);
            #pragma unroll
            for (int j = 0; j < 4; ++j) { bfr[j] = f2bf(lo[j]); bfr[4+j] = f2bf(hi[j]); }
        }
        f32x4 u[CCAP];
        #pragma unroll
        for (int tt = 0; tt < CCAP; ++tt) {
            bf16x8 afr = *reinterpret_cast<const bf16x8*>(
                Wf + ((size_t)r * CCAP + tt) * 128 + ln * 8);
            f32x4 z; z[0]=0.f; z[1]=0.f; z[2]=0.f; z[3]=0.f;
            u[tt] = __builtin_amdgcn_mfma_f32_16x16x32_bf16(afr, bfr, z, 0, 0, 0);
        }
        if (K > 0) {
            float a[CCAP];
            #pragma unroll
            for (int tt = 0; tt < CCAP; ++tt) {
                float p = u[tt][0]*vf[tt][0] + u[tt][1]*vf[tt][1]
                        + u[tt][2]*vf[tt][2] + u[tt][3]*vf[tt][3];
                p += __shfl_xor(p, 16);
                p += __shfl_xor(p, 32);
                a[tt] = p;
            }
            if (K == 2) {
                #pragma unroll
                for (int tt = 0; tt < CCAP; ++tt)
                    a[tt] += bf2f(bij[((size_t)r * CCAP + tt) * BB + b0 + ln]);
            } else {
                if (l < 16) {
                    #pragma unroll
                    for (int tt = 0; tt < CCAP; ++tt)
                        bij[((size_t)r * CCAP + tt) * BB + b0 + l] =
                            (unsigned short)f2bf(a[tt]);
                }
            }
            float m = a[0];
            #pragma unroll
            for (int tt = 1; tt < CCAP; ++tt) m = fmaxf(m, a[tt]);
            float ssum = 0.f;
            #pragma unroll
            for (int tt = 0; tt < CCAP; ++tt) { a[tt] = __expf(a[tt] - m); ssum += a[tt]; }
            float inv = 1.0f / ssum;
            #pragma unroll
            for (int tt = 0; tt < CCAP; ++tt) {
                float c = a[tt] * inv;
                sacc[tt][0] += c * u[tt][0];
                sacc[tt][1] += c * u[tt][1];
                sacc[tt][2] += c * u[tt][2];
                sacc[tt][3] += c * u[tt][3];
            }
        } else {
            #pragma unroll
            for (int tt = 0; tt < CCAP; ++tt) {
                sacc[tt][0] += u[tt][0]; sacc[tt][1] += u[tt][1];
                sacc[tt][2] += u[tt][2]; sacc[tt][3] += u[tt][3];
            }
        }
    }
    if (K == 0) {
        #pragma unroll
        for (int tt = 0; tt < CCAP; ++tt) {
            sacc[tt][0] *= 0.1f; sacc[tt][1] *= 0.1f;
            sacc[tt][2] *= 0.1f; sacc[tt][3] *= 0.1f;
        }
    }
    #pragma unroll
    for (int tt = 0; tt < CCAP; ++tt) {
        #pragma unroll
        for (int reg = 0; reg < 4; ++reg)
            part[w * 2720 + (tt * 16 + lg * 4 + reg) * 17 + ln] = sacc[tt][reg];
    }
    __syncthreads();
    float* Pu = P + (size_t)(bt * NSPLIT + sp) * 2560;
    for (int q = 0; q < 10; ++q) {
        const int idx = q * 256 + t;
        const int b16 = idx / 160, co = idx % 160;
        const int a0 = co * 17 + b16;
        Pu[idx] = part[a0] + part[2720 + a0] + part[5440 + a0] + part[8160 + a0];
    }
}

__global__ __launch_bounds__(256) void squash_merge(
    const float* __restrict__ P, const float* __restrict__ bias,
    float* __restrict__ v_out)
{
    const int idx = blockIdx.x * 256 + threadIdx.x;
    const int b = idx / CO, co = idx % CO;
    const int bt = b >> 4, b16 = b & 15;
    const float* base = P + (size_t)bt * NSPLIT * 2560 + b16 * CO + co;
    float sv = 0.f;
    #pragma unroll
    for (int sp = 0; sp < NSPLIT; ++sp) sv += base[(size_t)sp * 2560];
    sv += bias[co];
    float n2 = sv * sv;
    n2 += __shfl_xor(n2, 1);
    n2 += __shfl_xor(n2, 2);
    n2 += __shfl_xor(n2, 4);
    n2 += __shfl_xor(n2, 8);
    float norm = sqrtf(n2);
    float scale = norm / (1.0f + n2 + 1e-8f);
    v_out[idx] = scale * sv;
}

extern "C" void kernel_launch(void* const* d_in, const int* in_sizes, int n_in,
                              void* d_out, int out_size, void* d_ws, size_t ws_size,
                              hipStream_t stream) {
    const float* x    = (const float*)d_in[0];
    const float* W    = (const float*)d_in[1];
    const float* bias = (const float*)d_in[2];
    float* out = (float*)d_out;
    char* ws = (char*)d_ws;

    const dim3 blk(256);
    const dim3 rgrid(NBT * NSPLIT);   // 768

    if (ws_size >= 213581824ull) {
        // ---- streaming path ----
        float* v = (float*)(ws + 0);                         // 327,680 B
        float* s = (float*)(ws + 327680);                    // 327,680 B
        unsigned short* Wf = (unsigned short*)(ws + 655360); // 2,949,120 B
        unsigned short* xT = (unsigned short*)(ws + 3604480);// 9,437,184 B
        _Float16* bij = (_Float16*)(ws + 13041664);          // 11,796,480 B
        _Float16* U   = (_Float16*)(ws + 24838144);          // 188,743,680 B

        wconv<<<1440, blk, 0, stream>>>(W, Wf);
        xconv<<<2304, blk, 0, stream>>>(x, xT);

        hipMemsetAsync(s, 0, 81920 * sizeof(float), stream);
        produce_u<<<rgrid, blk, 0, stream>>>(xT, Wf, U, s);
        squash_plain<<<320, blk, 0, stream>>>(s, bias, v);

        hipMemsetAsync(s, 0, 81920 * sizeof(float), stream);
        consume_u<1><<<rgrid, blk, 0, stream>>>(U, v, bij, s);
        squash_plain<<<320, blk, 0, stream>>>(s, bias, v);

        hipMemsetAsync(s, 0, 81920 * sizeof(float), stream);
        consume_u<2><<<rgrid, blk, 0, stream>>>(U, v, bij, s);
        squash_plain<<<320, blk, 0, stream>>>(s, bias, out);
    } else {
        // ---- fallback: proven R8 path ----
        float* v = (float*)(ws + 0);
        float* P = v + 81920;
        unsigned short* bij = (unsigned short*)(ws + 8192000);
        unsigned short* Wf  = (unsigned short*)(ws + 19988480);

        wconv<<<1440, blk, 0, stream>>>(W, Wf);

        route2<0><<<rgrid, blk, 0, stream>>>(x, Wf, v, bij, P);
        squash_merge<<<320, blk, 0, stream>>>(P, bias, v);

        route2<1><<<rgrid, blk, 0, stream>>>(x, Wf, v, bij, P);
        squash_merge<<<320, blk, 0, stream>>>(P, bias, v);

        route2<2><<<rgrid, blk, 0, stream>>>(x, Wf, v, bij, P);
        squash_merge<<<320, blk, 0, stream>>>(P, bias, out);
    }
}